// Round 7
// baseline (292.667 us; speedup 1.0000x reference)
//
#include <hip/hip_runtime.h>

#define N_ROWS 200000
#define NTAP 9
#define BM 128
#define NBLK 1563                     // ceil(200000/128)
#define CSTRIDE 200                   // shorts per row per chunk: 192 payload + 8 pad
#define CHUNK_ELEMS (64*CSTRIDE)      // 12800 shorts = 25600 B per 3-tap chunk
#define WT_ELEMS (3*CHUNK_ELEMS)      // 38400 shorts per conv
#define TAB_ELEMS ((size_t)N_ROWS*64)
#define VEC8_CNT 1600000              // N*64/8

using bf16x8 = __attribute__((ext_vector_type(8))) __bf16;
using f32x4  = __attribute__((ext_vector_type(4))) float;

__device__ __forceinline__ float b2f(unsigned short u) {
  unsigned int x = ((unsigned int)u) << 16;
  return __builtin_bit_cast(float, x);
}
__device__ __forceinline__ unsigned short f2b(float f) {
  unsigned int x = __builtin_bit_cast(unsigned int, f);
  x = x + 0x7fffu + ((x >> 16) & 1u);
  return (unsigned short)(x >> 16);
}
__device__ __forceinline__ void async16(const void* g, void* l) {
  __builtin_amdgcn_global_load_lds((const __attribute__((address_space(1))) unsigned int*)g,
                                   (__attribute__((address_space(3))) unsigned int*)l,
                                   16, 0, 0);
}

// ---- idx [N][9] -> idxT [9][N] (coalesced per-tap loads in conv) ----
__global__ void transp_idx(const int* __restrict__ src, int* __restrict__ dst) {
  int i = blockIdx.x * 256 + threadIdx.x;
  if (i >= N_ROWS * NTAP) return;
  int n = i / NTAP, t = i - n * NTAP;
  dst[t * N_ROWS + n] = src[i];
}

// ---- cast x f32 -> bf16 table ----
__global__ void prep_x(const float* __restrict__ x, unsigned short* __restrict__ T) {
  int i = blockIdx.x * 256 + threadIdx.x;
  if (i >= VEC8_CNT) return;
  const float4* xv = (const float4*)x + (size_t)i * 2;
  float4 a = xv[0], b = xv[1];
  uint4 o;
  o.x = (unsigned)f2b(a.x) | ((unsigned)f2b(a.y) << 16);
  o.y = (unsigned)f2b(a.z) | ((unsigned)f2b(a.w) << 16);
  o.z = (unsigned)f2b(b.x) | ((unsigned)f2b(b.y) << 16);
  o.w = (unsigned)f2b(b.z) | ((unsigned)f2b(b.w) << 16);
  ((uint4*)T)[i] = o;
}

// ---- weight prep: chunked layout wt[chunk][co][200], payload k<192:
// wt[chunk][co][k] = bf16(w[3*chunk + k/64, k&63, co] * s[k&63]) ----
__global__ void prep_ws(const float* __restrict__ w, const float* __restrict__ stats,
                        unsigned short* __restrict__ wt) {
  int i = blockIdx.x * 256 + threadIdx.x;
  if (i >= WT_ELEMS) return;
  int chunk = i / CHUNK_ELEMS;
  int r = (i / CSTRIDE) & 63;
  int k = i % CSTRIDE;
  float v = 0.f;
  if (k < 192) {
    int tap = chunk * 3 + (k >> 6), ci = k & 63;
    float s = stats ? stats[ci] : 1.0f;
    v = w[tap * 4096 + ci * 64 + r] * s;
  }
  wt[i] = f2b(v);
}

// ---- bias[co] = sum_{tap,ci} b[ci] * w[tap,ci,co]  (f32 exact) ----
__global__ void prep_bias(const float* __restrict__ w, const float* __restrict__ stats,
                          float* __restrict__ bias) {
  int co = threadIdx.x & 63, part = threadIdx.x >> 6;
  float s = 0.f;
#pragma unroll 4
  for (int e = part; e < 576; e += 4) {
    int tap = e >> 6, ci = e & 63;
    s += stats[64 + ci] * w[tap * 4096 + ci * 64 + co];
  }
  __shared__ float r[4][64];
  r[part][co] = s;
  __syncthreads();
  if (part == 0) bias[co] = r[0][co] + r[1][co] + r[2][co] + r[3][co];
}

// ---- gather-GEMM, 3 blocks/CU: weight tile split into 3 double-buffered
// tap-chunks so LDS = 51200 B (was 78848). Occupancy is the one lever that
// has moved conv time (R0->R1); service-rate test at 24 waves/CU.
__global__ __launch_bounds__(512, 6) void conv_k(
    const unsigned short* __restrict__ T,     // [N][64] bf16 (lrelu'd prev layer)
    const int* __restrict__ idxT,             // [9][N]
    const unsigned short* __restrict__ Wt,    // [3][64][200] bf16, scale-folded
    const float* __restrict__ bias,           // [64] f32 or nullptr
    unsigned short* __restrict__ L,           // [N][64] bf16 out = lrelu(acc)
    float* __restrict__ partials)             // [2][64][NBLK] moments of lrelu
{
  __shared__ unsigned short Wlds[2][64][CSTRIDE];   // 51200 B total; psum aliases in

  const int tid = threadIdx.x;
  const int w = tid >> 6;
  const int l = tid & 63;
  const int blk = blockIdx.x;
  const int rowbase = blk * BM;
  const int kgrp = l >> 4;

  // stage chunks 0,1 into both buffers (linear global->LDS, pad in payload)
  for (int v = tid; v < 1600; v += 512) {
    async16(Wt + v * 8, (unsigned short*)&Wlds[0][0][0] + v * 8);
    async16(Wt + CHUNK_ELEMS + v * 8, (unsigned short*)&Wlds[1][0][0] + v * 8);
  }

  int mrow = rowbase + w * 16 + (l & 15);
  if (mrow > N_ROWS - 1) mrow = N_ROWS - 1;

  int ix[NTAP];
#pragma unroll
  for (int t = 0; t < NTAP; ++t) ix[t] = idxT[t * N_ROWS + mrow];

  float binit[4] = {0.f, 0.f, 0.f, 0.f};
  if (bias) {
#pragma unroll
    for (int f = 0; f < 4; ++f) binit[f] = bias[f * 16 + (l & 15)];
  }

  const char* Tb = (const char*)T;
  bf16x8 A0[NTAP], A1[NTAP];
#pragma unroll
  for (int t = 0; t < NTAP; ++t) {
    const char* p = Tb + (size_t)((unsigned)ix[t] * 128u) + kgrp * 16;
    A0[t] = *(const bf16x8*)p;
    A1[t] = *(const bf16x8*)(p + 64);
  }

  __syncthreads();   // drains staging + gathers (vmcnt0 before barrier)

  f32x4 acc[4];
#pragma unroll
  for (int f = 0; f < 4; ++f) acc[f] = (f32x4){binit[f], binit[f], binit[f], binit[f]};

#define MFMA_GROUP(buf, tbase)                                                  \
  {                                                                             \
    _Pragma("unroll")                                                           \
    for (int lt = 0; lt < 3; ++lt) {                                            \
      int t = (tbase) + lt;                                                     \
      const unsigned short* wb = &Wlds[buf][l & 15][lt * 64 + kgrp * 8];        \
      _Pragma("unroll")                                                         \
      for (int f = 0; f < 4; ++f) {                                             \
        bf16x8 b0 = *(const bf16x8*)(wb + f * 16 * CSTRIDE);                    \
        bf16x8 b1 = *(const bf16x8*)(wb + f * 16 * CSTRIDE + 32);               \
        acc[f] = __builtin_amdgcn_mfma_f32_16x16x32_bf16(A0[t], b0, acc[f], 0, 0, 0); \
        acc[f] = __builtin_amdgcn_mfma_f32_16x16x32_bf16(A1[t], b1, acc[f], 0, 0, 0); \
      }                                                                         \
    }                                                                           \
  }

  MFMA_GROUP(0, 0)          // taps 0-2
  __syncthreads();          // all waves done with buf0
  for (int v = tid; v < 1600; v += 512)
    async16(Wt + 2 * CHUNK_ELEMS + v * 8, (unsigned short*)&Wlds[0][0][0] + v * 8);
  MFMA_GROUP(1, 3)          // taps 3-5 while chunk2 streams in
  __syncthreads();          // drains chunk2 staging (vmcnt0 before barrier)
  MFMA_GROUP(2 & 0, 6)      // taps 6-8 from buf0
  __syncthreads();          // all reads of Wlds done -> safe to alias psum
#undef MFMA_GROUP

  float* psum = (float*)&Wlds[0][0][0];   // [8][2][64] alias
#pragma unroll
  for (int f = 0; f < 4; ++f) {
    int c = f * 16 + (l & 15);
    float sm = 0.f, sq = 0.f;
#pragma unroll
    for (int j = 0; j < 4; ++j) {
      int gr = rowbase + w * 16 + kgrp * 4 + j;   // C/D row = (lane>>4)*4 + reg
      float v = acc[f][j];
      float y = v >= 0.f ? v : 0.01f * v;
      if (gr < N_ROWS) {
        L[(size_t)gr * 64 + c] = f2b(y);
        sm += y; sq += y * y;
      }
    }
    sm += __shfl_xor(sm, 16); sm += __shfl_xor(sm, 32);
    sq += __shfl_xor(sq, 16); sq += __shfl_xor(sq, 32);
    if (l < 16) { psum[(w * 2 + 0) * 64 + c] = sm; psum[(w * 2 + 1) * 64 + c] = sq; }
  }
  __syncthreads();
  if (tid < 128) {
    int j = tid >> 6, c = tid & 63;
    float tot = 0.f;
#pragma unroll
    for (int ww = 0; ww < 8; ++ww) tot += psum[(ww * 2 + j) * 64 + c];
    partials[(size_t)(j * 64 + c) * NBLK + blk] = tot;
  }
}

// ---- finalize BN: per-channel scale/bias from moment partials ----
__global__ void reduce_k(const float* __restrict__ part, const float* __restrict__ gamma,
                         const float* __restrict__ beta, float* __restrict__ stats) {
  int c = blockIdx.x, t = threadIdx.x;
  float s = 0.f, q = 0.f;
  for (int b = t; b < NBLK; b += 256) {
    s += part[(size_t)c * NBLK + b];
    q += part[(size_t)(64 + c) * NBLK + b];
  }
#pragma unroll
  for (int m = 1; m < 64; m <<= 1) { s += __shfl_xor(s, m); q += __shfl_xor(q, m); }
  __shared__ float rs[4], rq[4];
  if ((t & 63) == 0) { rs[t >> 6] = s; rq[t >> 6] = q; }
  __syncthreads();
  if (t == 0) {
    float su = rs[0] + rs[1] + rs[2] + rs[3];
    float qu = rq[0] + rq[1] + rq[2] + rq[3];
    float mean = su / (float)N_ROWS;
    float var = qu / (float)N_ROWS - mean * mean;
    float r = rsqrtf(var + 1e-5f);
    float sc = gamma[c] * r;
    stats[c] = sc;
    stats[64 + c] = beta[c] - mean * sc;
  }
}

// ---- out = aff2(L2) + aff3(L3), L* already lrelu'd bf16 ----
__global__ void final_k(const unsigned short* __restrict__ L2v,
                        const unsigned short* __restrict__ L3v,
                        const float* __restrict__ st2, const float* __restrict__ st3,
                        float* __restrict__ out) {
  int i = blockIdx.x * 256 + threadIdx.x;
  if (i >= VEC8_CNT) return;
  uint4 av = ((const uint4*)L2v)[i];
  uint4 yv = ((const uint4*)L3v)[i];
  int c0 = (i & 7) * 8;
  unsigned va[4] = {av.x, av.y, av.z, av.w};
  unsigned vy[4] = {yv.x, yv.y, yv.z, yv.w};
  float o[8];
#pragma unroll
  for (int h = 0; h < 4; ++h) {
    int c = c0 + 2 * h;
    float a0 = b2f((unsigned short)(va[h] & 0xffff));
    float a1 = b2f((unsigned short)(va[h] >> 16));
    float y0 = b2f((unsigned short)(vy[h] & 0xffff));
    float y1 = b2f((unsigned short)(vy[h] >> 16));
    o[2 * h]     = a0 * st2[c]     + st2[64 + c]     + y0 * st3[c]     + st3[64 + c];
    o[2 * h + 1] = a1 * st2[c + 1] + st2[64 + c + 1] + y1 * st3[c + 1] + st3[64 + c + 1];
  }
  float4* ov = (float4*)(out + (size_t)i * 8);
  ov[0] = make_float4(o[0], o[1], o[2], o[3]);
  ov[1] = make_float4(o[4], o[5], o[6], o[7]);
}

extern "C" void kernel_launch(void* const* d_in, const int* in_sizes, int n_in,
                              void* d_out, int out_size, void* d_ws, size_t ws_size,
                              hipStream_t stream) {
  (void)in_sizes; (void)n_in; (void)out_size; (void)ws_size;
  const float* x    = (const float*)d_in[0];
  const float* w_a0 = (const float*)d_in[1];
  const float* g_a0 = (const float*)d_in[2];
  const float* b_a0 = (const float*)d_in[3];
  const float* w_a1 = (const float*)d_in[4];
  const float* g_a1 = (const float*)d_in[5];
  const float* b_a1 = (const float*)d_in[6];
  const float* w_b1 = (const float*)d_in[10];
  const float* g_b1 = (const float*)d_in[11];
  const float* b_b1 = (const float*)d_in[12];
  const int* idx133 = (const int*)d_in[13];
  const int* idx313 = (const int*)d_in[14];
  float* out = (float*)d_out;

  char* ws = (char*)d_ws;
  unsigned short* wt0 = (unsigned short*)ws;            // 3 * 76800 B
  unsigned short* wt1 = wt0 + WT_ELEMS;
  unsigned short* wt2 = wt1 + WT_ELEMS;
  unsigned short* Tx  = wt2 + WT_ELEMS;                 // conv1 input; reused as L3
  unsigned short* L1  = Tx + TAB_ELEMS;
  unsigned short* L2  = L1 + TAB_ELEMS;
  unsigned short* L3  = Tx;                             // alias: Tx dead after conv1
  int* it133 = (int*)(L2 + TAB_ELEMS);                  // 7.2 MB
  int* it313 = it133 + N_ROWS * NTAP;
  float* part = (float*)(it313 + N_ROWS * NTAP);        // 800 KB
  float* st1 = part + 2 * 64 * NBLK;
  float* st2 = st1 + 128;
  float* st3 = st2 + 128;
  float* bias1 = st3 + 128;
  float* bias2 = bias1 + 64;

  transp_idx<<<(N_ROWS * NTAP + 255) / 256, 256, 0, stream>>>(idx133, it133);
  transp_idx<<<(N_ROWS * NTAP + 255) / 256, 256, 0, stream>>>(idx313, it313);
  prep_x<<<(VEC8_CNT + 255) / 256, 256, 0, stream>>>(x, Tx);
  prep_ws<<<(WT_ELEMS + 255) / 256, 256, 0, stream>>>(w_a0, nullptr, wt0);

  conv_k<<<NBLK, 512, 0, stream>>>(Tx, it133, wt0, nullptr, L1, part);
  reduce_k<<<64, 256, 0, stream>>>(part, g_a0, b_a0, st1);
  prep_ws<<<(WT_ELEMS + 255) / 256, 256, 0, stream>>>(w_a1, st1, wt1);
  prep_bias<<<1, 256, 0, stream>>>(w_a1, st1, bias1);

  conv_k<<<NBLK, 512, 0, stream>>>(L1, it313, wt1, bias1, L2, part);
  reduce_k<<<64, 256, 0, stream>>>(part, g_a1, b_a1, st2);
  prep_ws<<<(WT_ELEMS + 255) / 256, 256, 0, stream>>>(w_b1, st2, wt2);
  prep_bias<<<1, 256, 0, stream>>>(w_b1, st2, bias2);

  conv_k<<<NBLK, 512, 0, stream>>>(L2, it133, wt2, bias2, L3, part);
  reduce_k<<<64, 256, 0, stream>>>(part, g_b1, b_b1, st3);

  final_k<<<(VEC8_CNT + 255) / 256, 256, 0, stream>>>(L2, L3, st2, st3, out);
}

// Round 8
// 212.728 us; speedup vs baseline: 1.3758x; 1.3758x over previous
//
#include <hip/hip_runtime.h>

#define N_ROWS 200000
#define NTAP 9
#define BM 128
#define NBLK 1563                     // ceil(200000/128)
#define WSTRIDE 584                   // padded shorts/row; 64*584*2 = 74752 = 73*1024
#define WCHUNKS 73
#define WT_ELEMS (64*WSTRIDE)
#define TAB_ELEMS ((size_t)N_ROWS*64)
#define VEC8_CNT 1600000              // N*64/8

#define TIDX_BLKS 7032                // ceil(1800000/256)
#define PX_BLKS 6250                  // 1600000/256
#define PW_BLKS 146                   // ceil(37376/256)

using bf16x8 = __attribute__((ext_vector_type(8))) __bf16;
using f32x4  = __attribute__((ext_vector_type(4))) float;

__device__ __forceinline__ float b2f(unsigned short u) {
  unsigned int x = ((unsigned int)u) << 16;
  return __builtin_bit_cast(float, x);
}
__device__ __forceinline__ unsigned short f2b(float f) {
  unsigned int x = __builtin_bit_cast(unsigned int, f);
  x = x + 0x7fffu + ((x >> 16) & 1u);
  return (unsigned short)(x >> 16);
}
__device__ __forceinline__ void async16(const void* g, void* l) {
  __builtin_amdgcn_global_load_lds((const __attribute__((address_space(1))) unsigned int*)g,
                                   (__attribute__((address_space(3))) unsigned int*)l,
                                   16, 0, 0);
}

__device__ __forceinline__ void wcast(const float* __restrict__ w,
                                      const float* __restrict__ stats,
                                      unsigned short* __restrict__ wt, int i) {
  int n = i / WSTRIDE, k = i - n * WSTRIDE;
  float v = 0.f;
  if (k < 576) {
    int tap = k >> 6, ci = k & 63;
    float s = stats ? stats[ci] : 1.0f;
    v = w[tap * 4096 + ci * 64 + n] * s;
  }
  wt[i] = f2b(v);
}

// ---- upfront fused prep: idx transposes, x cast, wt0 cast (one launch) ----
__global__ void prep0(const int* __restrict__ idx133, const int* __restrict__ idx313,
                      int* __restrict__ it133, int* __restrict__ it313,
                      const float* __restrict__ x, unsigned short* __restrict__ T,
                      const float* __restrict__ wa0, unsigned short* __restrict__ wt0) {
  int b = blockIdx.x;
  if (b < 2 * TIDX_BLKS) {
    const int* src = b < TIDX_BLKS ? idx133 : idx313;
    int* dst = b < TIDX_BLKS ? it133 : it313;
    int i = (b % TIDX_BLKS) * 256 + threadIdx.x;
    if (i < N_ROWS * NTAP) {
      int n = i / NTAP, t = i - n * NTAP;
      dst[t * N_ROWS + n] = src[i];
    }
    return;
  }
  b -= 2 * TIDX_BLKS;
  if (b < PX_BLKS) {
    int i = b * 256 + threadIdx.x;
    const float4* xv = (const float4*)x + (size_t)i * 2;
    float4 a = xv[0], c = xv[1];
    uint4 o;
    o.x = (unsigned)f2b(a.x) | ((unsigned)f2b(a.y) << 16);
    o.y = (unsigned)f2b(a.z) | ((unsigned)f2b(a.w) << 16);
    o.z = (unsigned)f2b(c.x) | ((unsigned)f2b(c.y) << 16);
    o.w = (unsigned)f2b(c.z) | ((unsigned)f2b(c.w) << 16);
    ((uint4*)T)[i] = o;
    return;
  }
  b -= PX_BLKS;
  int i = b * 256 + threadIdx.x;
  if (i < WT_ELEMS) wcast(wa0, nullptr, wt0, i);
}

// ---- per-boundary weight prep: blocks 0..PW_BLKS-1 cast+fold scale, last
// block computes folded bias (all inputs ready: stats from prior reduce_k) ----
__global__ void prep_next(const float* __restrict__ w, const float* __restrict__ stats,
                          unsigned short* __restrict__ wt, float* __restrict__ bias) {
  int b = blockIdx.x;
  if (b < PW_BLKS) {
    int i = b * 256 + threadIdx.x;
    if (i < WT_ELEMS) wcast(w, stats, wt, i);
    return;
  }
  // bias block: bias[co] = sum_{tap,ci} stats[64+ci] * w[tap,ci,co]
  int co = threadIdx.x & 63, part = threadIdx.x >> 6;
  float s = 0.f;
#pragma unroll 4
  for (int e = part; e < 576; e += 4) {
    int tap = e >> 6, ci = e & 63;
    s += stats[64 + ci] * w[tap * 4096 + ci * 64 + co];
  }
  __shared__ float r[4][64];
  r[part][co] = s;
  __syncthreads();
  if (part == 0) bias[co] = r[0][co] + r[1][co] + r[2][co] + r[3][co];
}

// ---- gather-GEMM with folded affine: acc = bias + sum_k T[ix_k] @ W'_k ----
// Memory-service bound at ~51us (R0-R6: every schedule variant lands here);
// proven R4 form: bound(512,4), sunk gathers, idxT, LDS weights.
__global__ __launch_bounds__(512, 4) void conv_k(
    const unsigned short* __restrict__ T,     // [N][64] bf16 (lrelu'd prev layer)
    const int* __restrict__ idxT,             // [9][N]
    const unsigned short* __restrict__ Wt,    // [64][584] bf16, scale-folded
    const float* __restrict__ bias,           // [64] f32 or nullptr
    unsigned short* __restrict__ L,           // [N][64] bf16 out = lrelu(acc)
    float* __restrict__ partials)             // [2][64][NBLK] moments of lrelu
{
  __shared__ unsigned short Wlds[64][WSTRIDE];
  __shared__ float psum[8][2][64];

  const int tid = threadIdx.x;
  const int w = tid >> 6;
  const int l = tid & 63;
  const int blk = blockIdx.x;
  const int rowbase = blk * BM;
  const int kgrp = l >> 4;

  // async weight staging straight to LDS (linear, matches padded global layout)
  for (int c = w; c < WCHUNKS; c += 8)
    async16(Wt + c * 512 + l * 8, (unsigned short*)&Wlds[0][0] + c * 512);

  int mrow = rowbase + w * 16 + (l & 15);
  if (mrow > N_ROWS - 1) mrow = N_ROWS - 1;

  int ix[NTAP];
#pragma unroll
  for (int t = 0; t < NTAP; ++t) ix[t] = idxT[t * N_ROWS + mrow];

  __syncthreads();   // Wlds ready (drains staging vmcnt); idx also landed

  const char* Tb = (const char*)T;
  bf16x8 A0[NTAP], A1[NTAP];
#pragma unroll
  for (int t = 0; t < NTAP; ++t) {
    const char* p = Tb + (size_t)((unsigned)ix[t] * 128u) + kgrp * 16;
    A0[t] = *(const bf16x8*)p;
    A1[t] = *(const bf16x8*)(p + 64);
  }

  float binit[4] = {0.f, 0.f, 0.f, 0.f};
  if (bias) {
#pragma unroll
    for (int f = 0; f < 4; ++f) binit[f] = bias[f * 16 + (l & 15)];
  }

  f32x4 acc[4];
#pragma unroll
  for (int f = 0; f < 4; ++f) acc[f] = (f32x4){binit[f], binit[f], binit[f], binit[f]};

#pragma unroll
  for (int t = 0; t < NTAP; ++t) {
    const unsigned short* wb = &Wlds[l & 15][t * 64 + kgrp * 8];
#pragma unroll
    for (int f = 0; f < 4; ++f) {
      bf16x8 b0 = *(const bf16x8*)(wb + f * 16 * WSTRIDE);
      bf16x8 b1 = *(const bf16x8*)(wb + f * 16 * WSTRIDE + 32);
      acc[f] = __builtin_amdgcn_mfma_f32_16x16x32_bf16(A0[t], b0, acc[f], 0, 0, 0);
      acc[f] = __builtin_amdgcn_mfma_f32_16x16x32_bf16(A1[t], b1, acc[f], 0, 0, 0);
    }
  }

  // epilogue: y = lrelu(acc); store bf16(y); per-channel moments of y
#pragma unroll
  for (int f = 0; f < 4; ++f) {
    int c = f * 16 + (l & 15);
    float sm = 0.f, sq = 0.f;
#pragma unroll
    for (int j = 0; j < 4; ++j) {
      int gr = rowbase + w * 16 + kgrp * 4 + j;   // C/D row = (lane>>4)*4 + reg
      float v = acc[f][j];
      float y = v >= 0.f ? v : 0.01f * v;
      if (gr < N_ROWS) {
        L[(size_t)gr * 64 + c] = f2b(y);
        sm += y; sq += y * y;
      }
    }
    sm += __shfl_xor(sm, 16); sm += __shfl_xor(sm, 32);
    sq += __shfl_xor(sq, 16); sq += __shfl_xor(sq, 32);
    if (l < 16) { psum[w][0][c] = sm; psum[w][1][c] = sq; }
  }
  __syncthreads();
  if (tid < 128) {
    int j = tid >> 6, c = tid & 63;
    float tot = 0.f;
#pragma unroll
    for (int ww = 0; ww < 8; ++ww) tot += psum[ww][j][c];
    partials[(size_t)(j * 64 + c) * NBLK + blk] = tot;
  }
}

// ---- finalize BN: per-channel scale/bias from moment partials ----
__global__ void reduce_k(const float* __restrict__ part, const float* __restrict__ gamma,
                         const float* __restrict__ beta, float* __restrict__ stats) {
  int c = blockIdx.x, t = threadIdx.x;
  float s = 0.f, q = 0.f;
  for (int b = t; b < NBLK; b += 256) {
    s += part[(size_t)c * NBLK + b];
    q += part[(size_t)(64 + c) * NBLK + b];
  }
#pragma unroll
  for (int m = 1; m < 64; m <<= 1) { s += __shfl_xor(s, m); q += __shfl_xor(q, m); }
  __shared__ float rs[4], rq[4];
  if ((t & 63) == 0) { rs[t >> 6] = s; rq[t >> 6] = q; }
  __syncthreads();
  if (t == 0) {
    float su = rs[0] + rs[1] + rs[2] + rs[3];
    float qu = rq[0] + rq[1] + rq[2] + rq[3];
    float mean = su / (float)N_ROWS;
    float var = qu / (float)N_ROWS - mean * mean;
    float r = rsqrtf(var + 1e-5f);
    float sc = gamma[c] * r;
    stats[c] = sc;
    stats[64 + c] = beta[c] - mean * sc;
  }
}

// ---- out = aff2(L2) + aff3(L3), L* already lrelu'd bf16 ----
__global__ void final_k(const unsigned short* __restrict__ L2v,
                        const unsigned short* __restrict__ L3v,
                        const float* __restrict__ st2, const float* __restrict__ st3,
                        float* __restrict__ out) {
  int i = blockIdx.x * 256 + threadIdx.x;
  if (i >= VEC8_CNT) return;
  uint4 av = ((const uint4*)L2v)[i];
  uint4 yv = ((const uint4*)L3v)[i];
  int c0 = (i & 7) * 8;
  unsigned va[4] = {av.x, av.y, av.z, av.w};
  unsigned vy[4] = {yv.x, yv.y, yv.z, yv.w};
  float o[8];
#pragma unroll
  for (int h = 0; h < 4; ++h) {
    int c = c0 + 2 * h;
    float a0 = b2f((unsigned short)(va[h] & 0xffff));
    float a1 = b2f((unsigned short)(va[h] >> 16));
    float y0 = b2f((unsigned short)(vy[h] & 0xffff));
    float y1 = b2f((unsigned short)(vy[h] >> 16));
    o[2 * h]     = a0 * st2[c]     + st2[64 + c]     + y0 * st3[c]     + st3[64 + c];
    o[2 * h + 1] = a1 * st2[c + 1] + st2[64 + c + 1] + y1 * st3[c + 1] + st3[64 + c + 1];
  }
  float4* ov = (float4*)(out + (size_t)i * 8);
  ov[0] = make_float4(o[0], o[1], o[2], o[3]);
  ov[1] = make_float4(o[4], o[5], o[6], o[7]);
}

extern "C" void kernel_launch(void* const* d_in, const int* in_sizes, int n_in,
                              void* d_out, int out_size, void* d_ws, size_t ws_size,
                              hipStream_t stream) {
  (void)in_sizes; (void)n_in; (void)out_size; (void)ws_size;
  const float* x    = (const float*)d_in[0];
  const float* w_a0 = (const float*)d_in[1];
  const float* g_a0 = (const float*)d_in[2];
  const float* b_a0 = (const float*)d_in[3];
  const float* w_a1 = (const float*)d_in[4];
  const float* g_a1 = (const float*)d_in[5];
  const float* b_a1 = (const float*)d_in[6];
  const float* w_b1 = (const float*)d_in[10];
  const float* g_b1 = (const float*)d_in[11];
  const float* b_b1 = (const float*)d_in[12];
  const int* idx133 = (const int*)d_in[13];
  const int* idx313 = (const int*)d_in[14];
  float* out = (float*)d_out;

  char* ws = (char*)d_ws;
  unsigned short* wt0 = (unsigned short*)ws;            // 3 * 74752 B
  unsigned short* wt1 = wt0 + WT_ELEMS;
  unsigned short* wt2 = wt1 + WT_ELEMS;
  unsigned short* Tx  = wt2 + WT_ELEMS;                 // conv1 input; reused as L3
  unsigned short* L1  = Tx + TAB_ELEMS;
  unsigned short* L2  = L1 + TAB_ELEMS;
  unsigned short* L3  = Tx;                             // alias: Tx dead after conv1
  int* it133 = (int*)(L2 + TAB_ELEMS);                  // 7.2 MB
  int* it313 = it133 + N_ROWS * NTAP;
  float* part = (float*)(it313 + N_ROWS * NTAP);        // 800 KB
  float* st1 = part + 2 * 64 * NBLK;
  float* st2 = st1 + 128;
  float* st3 = st2 + 128;
  float* bias1 = st3 + 128;
  float* bias2 = bias1 + 64;

  prep0<<<2 * TIDX_BLKS + PX_BLKS + PW_BLKS, 256, 0, stream>>>(
      idx133, idx313, it133, it313, x, Tx, w_a0, wt0);

  conv_k<<<NBLK, 512, 0, stream>>>(Tx, it133, wt0, nullptr, L1, part);
  reduce_k<<<64, 256, 0, stream>>>(part, g_a0, b_a0, st1);
  prep_next<<<PW_BLKS + 1, 256, 0, stream>>>(w_a1, st1, wt1, bias1);

  conv_k<<<NBLK, 512, 0, stream>>>(L1, it313, wt1, bias1, L2, part);
  reduce_k<<<64, 256, 0, stream>>>(part, g_a1, b_a1, st2);
  prep_next<<<PW_BLKS + 1, 256, 0, stream>>>(w_b1, st2, wt2, bias2);

  conv_k<<<NBLK, 512, 0, stream>>>(L2, it133, wt2, bias2, L3, part);
  reduce_k<<<64, 256, 0, stream>>>(part, g_b1, b_b1, st3);

  final_k<<<(VEC8_CNT + 255) / 256, 256, 0, stream>>>(L2, L3, st2, st3, out);
}

// Round 9
// 209.572 us; speedup vs baseline: 1.3965x; 1.0151x over previous
//
#include <hip/hip_runtime.h>

#define N_ROWS 200000
#define NTAP 9
#define BM 128
#define NBLK 1563                     // ceil(200000/128)
#define WSTRIDE 584                   // padded shorts/row; 64*584*2 = 74752 = 73*1024
#define WCHUNKS 73
#define WT_ELEMS (64*WSTRIDE)
#define TAB_ELEMS ((size_t)N_ROWS*64)
#define VEC8_CNT 1600000              // N*64/8

#define TIDX_BLKS 7032                // ceil(1800000/256)
#define PX_BLKS 6250                  // 1600000/256
#define PW_BLKS 146                   // ceil(37376/256)

using bf16x8 = __attribute__((ext_vector_type(8))) __bf16;
using f32x4  = __attribute__((ext_vector_type(4))) float;

__device__ __forceinline__ float b2f(unsigned short u) {
  unsigned int x = ((unsigned int)u) << 16;
  return __builtin_bit_cast(float, x);
}
__device__ __forceinline__ unsigned short f2b(float f) {
  unsigned int x = __builtin_bit_cast(unsigned int, f);
  x = x + 0x7fffu + ((x >> 16) & 1u);
  return (unsigned short)(x >> 16);
}
__device__ __forceinline__ void async16(const void* g, void* l) {
  __builtin_amdgcn_global_load_lds((const __attribute__((address_space(1))) unsigned int*)g,
                                   (__attribute__((address_space(3))) unsigned int*)l,
                                   16, 0, 0);
}

__device__ __forceinline__ void wcast(const float* __restrict__ w,
                                      const float* __restrict__ stats,
                                      unsigned short* __restrict__ wt, int i) {
  int n = i / WSTRIDE, k = i - n * WSTRIDE;
  float v = 0.f;
  if (k < 576) {
    int tap = k >> 6, ci = k & 63;
    float s = stats ? stats[ci] : 1.0f;
    v = w[tap * 4096 + ci * 64 + n] * s;
  }
  wt[i] = f2b(v);
}

// ---- upfront fused prep: idx transposes, x cast, wt0 cast (one launch) ----
__global__ void prep0(const int* __restrict__ idx133, const int* __restrict__ idx313,
                      int* __restrict__ it133, int* __restrict__ it313,
                      const float* __restrict__ x, unsigned short* __restrict__ T,
                      const float* __restrict__ wa0, unsigned short* __restrict__ wt0) {
  int b = blockIdx.x;
  if (b < 2 * TIDX_BLKS) {
    const int* src = b < TIDX_BLKS ? idx133 : idx313;
    int* dst = b < TIDX_BLKS ? it133 : it313;
    int i = (b % TIDX_BLKS) * 256 + threadIdx.x;
    if (i < N_ROWS * NTAP) {
      int n = i / NTAP, t = i - n * NTAP;
      dst[t * N_ROWS + n] = src[i];
    }
    return;
  }
  b -= 2 * TIDX_BLKS;
  if (b < PX_BLKS) {
    int i = b * 256 + threadIdx.x;
    const float4* xv = (const float4*)x + (size_t)i * 2;
    float4 a = xv[0], c = xv[1];
    uint4 o;
    o.x = (unsigned)f2b(a.x) | ((unsigned)f2b(a.y) << 16);
    o.y = (unsigned)f2b(a.z) | ((unsigned)f2b(a.w) << 16);
    o.z = (unsigned)f2b(c.x) | ((unsigned)f2b(c.y) << 16);
    o.w = (unsigned)f2b(c.z) | ((unsigned)f2b(c.w) << 16);
    ((uint4*)T)[i] = o;
    return;
  }
  b -= PX_BLKS;
  int i = b * 256 + threadIdx.x;
  if (i < WT_ELEMS) wcast(wa0, nullptr, wt0, i);
}

// ---- per-boundary weight prep: blocks 0..PW_BLKS-1 cast+fold scale, last
// block computes folded bias (all inputs ready: stats from prior reduce_k) ----
__global__ void prep_next(const float* __restrict__ w, const float* __restrict__ stats,
                          unsigned short* __restrict__ wt, float* __restrict__ bias) {
  int b = blockIdx.x;
  if (b < PW_BLKS) {
    int i = b * 256 + threadIdx.x;
    if (i < WT_ELEMS) wcast(w, stats, wt, i);
    return;
  }
  // bias block: bias[co] = sum_{tap,ci} stats[64+ci] * w[tap,ci,co]
  int co = threadIdx.x & 63, part = threadIdx.x >> 6;
  float s = 0.f;
#pragma unroll 4
  for (int e = part; e < 576; e += 4) {
    int tap = e >> 6, ci = e & 63;
    s += stats[64 + ci] * w[tap * 4096 + ci * 64 + co];
  }
  __shared__ float r[4][64];
  r[part][co] = s;
  __syncthreads();
  if (part == 0) bias[co] = r[0][co] + r[1][co] + r[2][co] + r[3][co];
}

// ---- gather-GEMM with folded affine: acc = bias + sum_k T[ix_k] @ W'_k ----
// sched_group_barrier enforces: 18 gathers issue as one cluster (parallel
// latency), then per-tap {8 ds_read, 8 MFMA}. T19 used for ORDER, not perf.
__global__ __launch_bounds__(512, 4) void conv_k(
    const unsigned short* __restrict__ T,     // [N][64] bf16 (lrelu'd prev layer)
    const int* __restrict__ idxT,             // [9][N]
    const unsigned short* __restrict__ Wt,    // [64][584] bf16, scale-folded
    const float* __restrict__ bias,           // [64] f32 or nullptr
    unsigned short* __restrict__ L,           // [N][64] bf16 out = lrelu(acc)
    float* __restrict__ partials)             // [2][64][NBLK] moments of lrelu
{
  __shared__ unsigned short Wlds[64][WSTRIDE];
  __shared__ float psum[8][2][64];

  const int tid = threadIdx.x;
  const int w = tid >> 6;
  const int l = tid & 63;
  const int blk = blockIdx.x;
  const int rowbase = blk * BM;
  const int kgrp = l >> 4;

  // async weight staging straight to LDS (linear, matches padded global layout)
  for (int c = w; c < WCHUNKS; c += 8)
    async16(Wt + c * 512 + l * 8, (unsigned short*)&Wlds[0][0] + c * 512);

  int mrow = rowbase + w * 16 + (l & 15);
  if (mrow > N_ROWS - 1) mrow = N_ROWS - 1;

  int ix[NTAP];
#pragma unroll
  for (int t = 0; t < NTAP; ++t) ix[t] = idxT[t * N_ROWS + mrow];

  float binit[4] = {0.f, 0.f, 0.f, 0.f};
  if (bias) {
#pragma unroll
    for (int f = 0; f < 4; ++f) binit[f] = bias[f * 16 + (l & 15)];
  }

  __syncthreads();   // Wlds ready (drains staging vmcnt); idx/bias also landed

  // -------- scheduling-pinned region: gathers clustered ahead of MFMAs ------
  const char* Tb = (const char*)T;
  bf16x8 A0[NTAP], A1[NTAP];
#pragma unroll
  for (int t = 0; t < NTAP; ++t) {
    const char* p = Tb + (size_t)((unsigned)ix[t] * 128u) + kgrp * 16;
    A0[t] = *(const bf16x8*)p;
    A1[t] = *(const bf16x8*)(p + 64);
  }
  // all 18 global_load_dwordx4 first (one parallel latency round)
  __builtin_amdgcn_sched_group_barrier(0x20, 18, 0);   // VMEM_READ x18

  f32x4 acc[4];
#pragma unroll
  for (int f = 0; f < 4; ++f) acc[f] = (f32x4){binit[f], binit[f], binit[f], binit[f]};

#pragma unroll
  for (int t = 0; t < NTAP; ++t) {
    const unsigned short* wb = &Wlds[l & 15][t * 64 + kgrp * 8];
#pragma unroll
    for (int f = 0; f < 4; ++f) {
      bf16x8 b0 = *(const bf16x8*)(wb + f * 16 * WSTRIDE);
      bf16x8 b1 = *(const bf16x8*)(wb + f * 16 * WSTRIDE + 32);
      acc[f] = __builtin_amdgcn_mfma_f32_16x16x32_bf16(A0[t], b0, acc[f], 0, 0, 0);
      acc[f] = __builtin_amdgcn_mfma_f32_16x16x32_bf16(A1[t], b1, acc[f], 0, 0, 0);
    }
    __builtin_amdgcn_sched_group_barrier(0x100, 8, 0); // DS_READ x8 (this tap)
    __builtin_amdgcn_sched_group_barrier(0x8, 8, 0);   // MFMA x8 (this tap)
  }

  // epilogue: y = lrelu(acc); store bf16(y); per-channel moments of y
#pragma unroll
  for (int f = 0; f < 4; ++f) {
    int c = f * 16 + (l & 15);
    float sm = 0.f, sq = 0.f;
#pragma unroll
    for (int j = 0; j < 4; ++j) {
      int gr = rowbase + w * 16 + kgrp * 4 + j;   // C/D row = (lane>>4)*4 + reg
      float v = acc[f][j];
      float y = v >= 0.f ? v : 0.01f * v;
      if (gr < N_ROWS) {
        L[(size_t)gr * 64 + c] = f2b(y);
        sm += y; sq += y * y;
      }
    }
    sm += __shfl_xor(sm, 16); sm += __shfl_xor(sm, 32);
    sq += __shfl_xor(sq, 16); sq += __shfl_xor(sq, 32);
    if (l < 16) { psum[w][0][c] = sm; psum[w][1][c] = sq; }
  }
  __syncthreads();
  if (tid < 128) {
    int j = tid >> 6, c = tid & 63;
    float tot = 0.f;
#pragma unroll
    for (int ww = 0; ww < 8; ++ww) tot += psum[ww][j][c];
    partials[(size_t)(j * 64 + c) * NBLK + blk] = tot;
  }
}

// ---- finalize BN: per-channel scale/bias from moment partials ----
__global__ void reduce_k(const float* __restrict__ part, const float* __restrict__ gamma,
                         const float* __restrict__ beta, float* __restrict__ stats) {
  int c = blockIdx.x, t = threadIdx.x;
  float s = 0.f, q = 0.f;
  for (int b = t; b < NBLK; b += 256) {
    s += part[(size_t)c * NBLK + b];
    q += part[(size_t)(64 + c) * NBLK + b];
  }
#pragma unroll
  for (int m = 1; m < 64; m <<= 1) { s += __shfl_xor(s, m); q += __shfl_xor(q, m); }
  __shared__ float rs[4], rq[4];
  if ((t & 63) == 0) { rs[t >> 6] = s; rq[t >> 6] = q; }
  __syncthreads();
  if (t == 0) {
    float su = rs[0] + rs[1] + rs[2] + rs[3];
    float qu = rq[0] + rq[1] + rq[2] + rq[3];
    float mean = su / (float)N_ROWS;
    float var = qu / (float)N_ROWS - mean * mean;
    float r = rsqrtf(var + 1e-5f);
    float sc = gamma[c] * r;
    stats[c] = sc;
    stats[64 + c] = beta[c] - mean * sc;
  }
}

// ---- out = aff2(L2) + aff3(L3), L* already lrelu'd bf16 ----
__global__ void final_k(const unsigned short* __restrict__ L2v,
                        const unsigned short* __restrict__ L3v,
                        const float* __restrict__ st2, const float* __restrict__ st3,
                        float* __restrict__ out) {
  int i = blockIdx.x * 256 + threadIdx.x;
  if (i >= VEC8_CNT) return;
  uint4 av = ((const uint4*)L2v)[i];
  uint4 yv = ((const uint4*)L3v)[i];
  int c0 = (i & 7) * 8;
  unsigned va[4] = {av.x, av.y, av.z, av.w};
  unsigned vy[4] = {yv.x, yv.y, yv.z, yv.w};
  float o[8];
#pragma unroll
  for (int h = 0; h < 4; ++h) {
    int c = c0 + 2 * h;
    float a0 = b2f((unsigned short)(va[h] & 0xffff));
    float a1 = b2f((unsigned short)(va[h] >> 16));
    float y0 = b2f((unsigned short)(vy[h] & 0xffff));
    float y1 = b2f((unsigned short)(vy[h] >> 16));
    o[2 * h]     = a0 * st2[c]     + st2[64 + c]     + y0 * st3[c]     + st3[64 + c];
    o[2 * h + 1] = a1 * st2[c + 1] + st2[64 + c + 1] + y1 * st3[c + 1] + st3[64 + c + 1];
  }
  float4* ov = (float4*)(out + (size_t)i * 8);
  ov[0] = make_float4(o[0], o[1], o[2], o[3]);
  ov[1] = make_float4(o[4], o[5], o[6], o[7]);
}

extern "C" void kernel_launch(void* const* d_in, const int* in_sizes, int n_in,
                              void* d_out, int out_size, void* d_ws, size_t ws_size,
                              hipStream_t stream) {
  (void)in_sizes; (void)n_in; (void)out_size; (void)ws_size;
  const float* x    = (const float*)d_in[0];
  const float* w_a0 = (const float*)d_in[1];
  const float* g_a0 = (const float*)d_in[2];
  const float* b_a0 = (const float*)d_in[3];
  const float* w_a1 = (const float*)d_in[4];
  const float* g_a1 = (const float*)d_in[5];
  const float* b_a1 = (const float*)d_in[6];
  const float* w_b1 = (const float*)d_in[10];
  const float* g_b1 = (const float*)d_in[11];
  const float* b_b1 = (const float*)d_in[12];
  const int* idx133 = (const int*)d_in[13];
  const int* idx313 = (const int*)d_in[14];
  float* out = (float*)d_out;

  char* ws = (char*)d_ws;
  unsigned short* wt0 = (unsigned short*)ws;            // 3 * 74752 B
  unsigned short* wt1 = wt0 + WT_ELEMS;
  unsigned short* wt2 = wt1 + WT_ELEMS;
  unsigned short* Tx  = wt2 + WT_ELEMS;                 // conv1 input; reused as L3
  unsigned short* L1  = Tx + TAB_ELEMS;
  unsigned short* L2  = L1 + TAB_ELEMS;
  unsigned short* L3  = Tx;                             // alias: Tx dead after conv1
  int* it133 = (int*)(L2 + TAB_ELEMS);                  // 7.2 MB
  int* it313 = it133 + N_ROWS * NTAP;
  float* part = (float*)(it313 + N_ROWS * NTAP);        // 800 KB
  float* st1 = part + 2 * 64 * NBLK;
  float* st2 = st1 + 128;
  float* st3 = st2 + 128;
  float* bias1 = st3 + 128;
  float* bias2 = bias1 + 64;

  prep0<<<2 * TIDX_BLKS + PX_BLKS + PW_BLKS, 256, 0, stream>>>(
      idx133, idx313, it133, it313, x, Tx, w_a0, wt0);

  conv_k<<<NBLK, 512, 0, stream>>>(Tx, it133, wt0, nullptr, L1, part);
  reduce_k<<<64, 256, 0, stream>>>(part, g_a0, b_a0, st1);
  prep_next<<<PW_BLKS + 1, 256, 0, stream>>>(w_a1, st1, wt1, bias1);

  conv_k<<<NBLK, 512, 0, stream>>>(L1, it313, wt1, bias1, L2, part);
  reduce_k<<<64, 256, 0, stream>>>(part, g_a1, b_a1, st2);
  prep_next<<<PW_BLKS + 1, 256, 0, stream>>>(w_b1, st2, wt2, bias2);

  conv_k<<<NBLK, 512, 0, stream>>>(L2, it133, wt2, bias2, L3, part);
  reduce_k<<<64, 256, 0, stream>>>(part, g_b1, b_b1, st3);

  final_k<<<(VEC8_CNT + 255) / 256, 256, 0, stream>>>(L2, L3, st2, st3, out);
}